// Round 10
// baseline (1561.182 us; speedup 1.0000x reference)
//
#include <hip/hip_runtime.h>
#include <math.h>

// CollapseEngine R10: R9 numerics (pure RNE bf16 MFMA), but 32 batch rows per
// wave as TWO 16-col tiles sharing each A-frag ds_read -> LDS reads per FLOP
// halve (the 45% LDS-pipe floor), blocks halve (grid 512, 1 block/CU at
// ~240 VGPR, launch_bounds(512,2)). G2 accumulates in-place into h-state.
// ws layout / wsplit / counted-vmcnt pipeline identical to R9.
// phi(ks,G,i) = 32*ks + 16*(i>>2) + 4*G + (i&3),  G = lane>>4.

#define DIMX 256
#define NL 6
#define CPAD 68   // padded float stride for per-G const arrays

typedef float f32x4 __attribute__((ext_vector_type(4)));
typedef short short8 __attribute__((ext_vector_type(8)));
typedef unsigned int u32x4 __attribute__((ext_vector_type(4)));

// 16 chunks of 1024 granules (16KB); chunk c = (g*2+pass)*4 + kk, kk=ks>>1
#define CHB(c) ((c) * 1024)

// RNE-pack f32 pair -> u32 of 2 bf16 (lo = X0, hi = X1)
#define PACKB(X0, X1, DST)                                                       \
    asm("v_cvt_pk_bf16_f32 %0, %1, %2" : "=v"(DST) : "v"(X0), "v"(X1));

// ---------------- W RNE-bf16 frag precompute (phi-ordered, = R9) ----------------
__global__ void wsplit(const float* __restrict__ W1, const float* __restrict__ W2,
                       u32x4* __restrict__ ws) {
    int gi   = blockIdx.x * 256 + threadIdx.x;      // 0..16383
    int ln   = gi & 63;
    int t8   = (gi >> 6) & 7;
    int ks2  = (gi >> 9) & 1;
    int kk   = (gi >> 10) & 3;
    int pass = (gi >> 12) & 1;
    int g    = (gi >> 13) & 1;
    int ks   = kk * 2 + ks2;
    int m    = (pass * 8 + t8) * 16 + (ln & 15);
    int G    = ln >> 4;
    const float* Wg = g ? W2 : W1;
    unsigned o[4];
#pragma unroll
    for (int p = 0; p < 4; ++p) {
        int f = 32 * ks + ((p >> 1) << 4) + 4 * G + ((p & 1) << 1);
        float x0 = Wg[m * DIMX + f];
        float x1 = Wg[m * DIMX + f + 1];
        unsigned hp;
        PACKB(x0, x1, hp);
        o[p] = hp;
    }
    u32x4 out = {o[0], o[1], o[2], o[3]};
    ws[gi] = out;
}

// ---------------- main fused kernel ----------------

// stage one 16KB chunk (1024 granules): 512 thr x 2 x 16B
#define STAGE(gIdxBase, ldsSlotBase)                                             \
    {                                                                            \
        _Pragma("unroll")                                                        \
        for (int i_ = 0; i_ < 2; ++i_) {                                         \
            const int off_ = ((w * 2 + i_) << 6);                                \
            __builtin_amdgcn_global_load_lds(                                    \
                (const __attribute__((address_space(1))) void*)(ws + (gIdxBase) + off_ + lane), \
                (__attribute__((address_space(3))) void*)(&wf[(ldsSlotBase) + off_]),           \
                16, 0, 0);                                                       \
        }                                                                        \
    }

#define PIPE_SYNC()                                                              \
    {                                                                            \
        asm volatile("s_waitcnt vmcnt(4)" ::: "memory");                         \
        __builtin_amdgcn_sched_barrier(0);                                       \
        __builtin_amdgcn_s_barrier();                                            \
        __builtin_amdgcn_sched_barrier(0);                                       \
    }

__global__ __launch_bounds__(512, 2)
void collapse_mfma16(const float* __restrict__ h0,
                     const float* __restrict__ b1f,
                     const float* __restrict__ b2f,
                     const float* __restrict__ anchors,
                     const u32x4* __restrict__ ws,
                     float* __restrict__ out_h,
                     float* __restrict__ out_align,
                     float* __restrict__ out_div,
                     float* __restrict__ out_tens,
                     int B)
{
    __shared__ __align__(16) u32x4 wf[4096];         // 4 x 16KB W-frag buffers
    __shared__ __align__(16) float an_reg[3][272];   // padded (stride CPAD=68)
    __shared__ __align__(16) float b1_reg[272];
    __shared__ __align__(16) float b2_reg[272];
    __shared__ float an_inv[3];

    const int tid  = threadIdx.x;
    const int w    = tid >> 6;
    const int lane = tid & 63;
    const int G    = lane >> 4;          // k-octet / D-row group
    const int c    = lane & 15;          // batch col within wave tile
    const int bglob = blockIdx.x * 256 + w * 32 + c;   // tile0 row; tile1 = +16

    // anchor inverse norms (waves 0..2)
    if (w < 3) {
        const float4 av = *(const float4*)&anchors[w * DIMX + lane * 4];
        float ss = av.x * av.x + av.y * av.y + av.z * av.z + av.w * av.w;
#pragma unroll
        for (int m = 1; m < 64; m <<= 1) ss += __shfl_xor(ss, m, 64);
        if (lane == 0) an_inv[w] = 1.0f / fmaxf(sqrtf(ss), 1e-12f);
    }
    __syncthreads();

    // const arrays in phi-layout, padded
    {
        int idx = tid & 255;
        int Gc = idx >> 6, s = idx & 63;
        int f = 16 * (s >> 2) + 4 * Gc + (s & 3);
        int pidx = Gc * CPAD + s;
        if (tid < 256) {
            b1_reg[pidx] = b1f[f];
            b2_reg[pidx] = b2f[f];
        } else {
#pragma unroll
            for (int k = 0; k < 3; ++k)
                an_reg[k][pidx] = anchors[k * DIMX + f] * an_inv[k];
        }
    }
    __syncthreads();

    // h state: h4[bt*16+mt] = h[row bglob+bt*16][16mt+4G+r], r in vector comps
    f32x4 h4[32];
#pragma unroll
    for (int bt = 0; bt < 2; ++bt) {
#pragma unroll
        for (int mt = 0; mt < 16; ++mt) {
            const float4 v = *(const float4*)
                &h0[(size_t)(bglob + bt*16) * DIMX + 16 * mt + 4 * G];
            h4[bt*16+mt][0] = v.x; h4[bt*16+mt][1] = v.y;
            h4[bt*16+mt][2] = v.z; h4[bt*16+mt][3] = v.w;
        }
    }

    // pipeline prologue: prefetch chunks 0,1,2 into bufs 0,1,2
    STAGE(CHB(0), 0);
    STAGE(CHB(1), 1024);
    STAGE(CHB(2), 2048);

#pragma unroll 1
    for (int layer = 0; layer < NL; ++layer) {
        // ---------- stats (both tiles; shared anchor loads) ----------
        float p0[2] = {0,0}, d0[2] = {0,0}, d1[2] = {0,0}, d2[2] = {0,0};
#pragma unroll
        for (int q = 0; q < 16; ++q) {
            const float4 a0 = *(const float4*)&an_reg[0][G * CPAD + q * 4];
            const float4 a1 = *(const float4*)&an_reg[1][G * CPAD + q * 4];
            const float4 a2 = *(const float4*)&an_reg[2][G * CPAD + q * 4];
#pragma unroll
            for (int bt = 0; bt < 2; ++bt) {
                float x;
                x = h4[bt*16+q][0]; p0[bt]+=x*x; d0[bt]+=x*a0.x; d1[bt]+=x*a1.x; d2[bt]+=x*a2.x;
                x = h4[bt*16+q][1]; p0[bt]+=x*x; d0[bt]+=x*a0.y; d1[bt]+=x*a1.y; d2[bt]+=x*a2.y;
                x = h4[bt*16+q][2]; p0[bt]+=x*x; d0[bt]+=x*a0.z; d1[bt]+=x*a1.z; d2[bt]+=x*a2.z;
                x = h4[bt*16+q][3]; p0[bt]+=x*x; d0[bt]+=x*a0.w; d1[bt]+=x*a1.w; d2[bt]+=x*a2.w;
            }
        }
        float cf0[2], cf1[2], cf2[2], csum[2];
#pragma unroll
        for (int bt = 0; bt < 2; ++bt) {
            p0[bt] += __shfl_xor(p0[bt], 16); d0[bt] += __shfl_xor(d0[bt], 16);
            d1[bt] += __shfl_xor(d1[bt], 16); d2[bt] += __shfl_xor(d2[bt], 16);
            p0[bt] += __shfl_xor(p0[bt], 32); d0[bt] += __shfl_xor(d0[bt], 32);
            d1[bt] += __shfl_xor(d1[bt], 32); d2[bt] += __shfl_xor(d2[bt], 32);
            const float inv_rn = 1.0f / fmaxf(sqrtf(p0[bt]), 1e-12f);
            const float al0 = d0[bt]*inv_rn, al1 = d1[bt]*inv_rn, al2 = d2[bt]*inv_rn;
            const float dv0 = 1.0f-al0, dv1 = 1.0f-al1, dv2 = 1.0f-al2;
            cf0[bt] = -0.10f*dv0 / fmaxf(sqrtf(fmaxf(p0[bt]-2.0f*d0[bt]+1.0f, 0.0f)), 1e-12f);
            cf1[bt] = -0.10f*dv1 / fmaxf(sqrtf(fmaxf(p0[bt]-2.0f*d1[bt]+1.0f, 0.0f)), 1e-12f);
            cf2[bt] = -0.05f*dv2 / fmaxf(sqrtf(fmaxf(p0[bt]-2.0f*d2[bt]+1.0f, 0.0f)), 1e-12f);
            csum[bt] = 1.0f + cf0[bt] + cf1[bt] + cf2[bt];
            if (G == 0) {
                const long long tb = ((long long)layer*B + (bglob + bt*16))*3;
                out_align[tb+0]=al0; out_align[tb+1]=al1; out_align[tb+2]=al2;
                out_div[tb+0]=dv0;   out_div[tb+1]=dv1;   out_div[tb+2]=dv2;
                out_tens[tb+0]=dv0*dv0; out_tens[tb+1]=dv1*dv1; out_tens[tb+2]=dv2*dv2;
            }
        }

        // ---------- G1: t = tanh(W1 h + b1); 2 passes of 8 out-tiles ----------
        unsigned tph[2][32];
#pragma unroll
        for (int pass = 0; pass < 2; ++pass) {
            f32x4 ac[2][8];
#pragma unroll
            for (int bt = 0; bt < 2; ++bt)
#pragma unroll
                for (int j = 0; j < 8; ++j) ac[bt][j] = (f32x4)(0.0f);
#pragma unroll
            for (int kk = 0; kk < 4; ++kk) {
                const int s = pass * 4 + kk;
                PIPE_SYNC();
                STAGE(CHB((s + 3) & 15), ((s + 3) & 3) * 1024);
                const int cb = (s & 3) * 1024;
#pragma unroll
                for (int ks2 = 0; ks2 < 2; ++ks2) {
                    const int ks = kk * 2 + ks2;
                    short8 Bh[2];
#pragma unroll
                    for (int bt = 0; bt < 2; ++bt) {
                        unsigned bh0, bh1, bh2, bh3;
                        PACKB(h4[bt*16+2*ks][0],   h4[bt*16+2*ks][1],   bh0);
                        PACKB(h4[bt*16+2*ks][2],   h4[bt*16+2*ks][3],   bh1);
                        PACKB(h4[bt*16+2*ks+1][0], h4[bt*16+2*ks+1][1], bh2);
                        PACKB(h4[bt*16+2*ks+1][2], h4[bt*16+2*ks+1][3], bh3);
                        u32x4 tb_ = {bh0, bh1, bh2, bh3};
                        Bh[bt] = __builtin_bit_cast(short8, tb_);
                    }
#pragma unroll
                    for (int j = 0; j < 8; ++j) {
                        const short8 Ah = __builtin_bit_cast(short8,
                            wf[cb + ks2*512 + j*64 + lane]);
                        ac[0][j] = __builtin_amdgcn_mfma_f32_16x16x32_bf16(Ah, Bh[0], ac[0][j], 0, 0, 0);
                        ac[1][j] = __builtin_amdgcn_mfma_f32_16x16x32_bf16(Ah, Bh[1], ac[1][j], 0, 0, 0);
                    }
                }
            }
            // tanh + b1, pack into t (phi-layout)
#pragma unroll
            for (int j = 0; j < 8; ++j) {
                const int mt = pass * 8 + j;
                const float4 bq = *(const float4*)&b1_reg[G * CPAD + mt * 4];
                const int ti = 4 * (mt >> 1) + 2 * (mt & 1);
#pragma unroll
                for (int bt = 0; bt < 2; ++bt) {
                    float tv[4];
#pragma unroll
                    for (int r = 0; r < 4; ++r) {
                        float x = ac[bt][j][r] + ((r==0)?bq.x:(r==1)?bq.y:(r==2)?bq.z:bq.w);
                        float e = __expf(2.0f * x);
                        tv[r] = 1.0f - 2.0f * __builtin_amdgcn_rcpf(e + 1.0f);
                    }
                    PACKB(tv[0], tv[1], tph[bt][ti]);
                    PACKB(tv[2], tv[3], tph[bt][ti + 1]);
                }
            }
        }

        // ---------- G2: h' = (h + b2 + force) + W2 t, in-place into h4 ----------
#pragma unroll
        for (int pass = 0; pass < 2; ++pass) {
            // init this pass's 8 tiles in place
#pragma unroll
            for (int j = 0; j < 8; ++j) {
                const int mt = pass * 8 + j;
                const float4 a0 = *(const float4*)&an_reg[0][G * CPAD + mt * 4];
                const float4 a1 = *(const float4*)&an_reg[1][G * CPAD + mt * 4];
                const float4 a2 = *(const float4*)&an_reg[2][G * CPAD + mt * 4];
                const float4 bq = *(const float4*)&b2_reg[G * CPAD + mt * 4];
#pragma unroll
                for (int bt = 0; bt < 2; ++bt) {
                    f32x4 hv = h4[bt*16+mt];
                    hv[0] = hv[0]*csum[bt] - (cf0[bt]*a0.x + cf1[bt]*a1.x + cf2[bt]*a2.x) + bq.x;
                    hv[1] = hv[1]*csum[bt] - (cf0[bt]*a0.y + cf1[bt]*a1.y + cf2[bt]*a2.y) + bq.y;
                    hv[2] = hv[2]*csum[bt] - (cf0[bt]*a0.z + cf1[bt]*a1.z + cf2[bt]*a2.z) + bq.z;
                    hv[3] = hv[3]*csum[bt] - (cf0[bt]*a0.w + cf1[bt]*a1.w + cf2[bt]*a2.w) + bq.w;
                    h4[bt*16+mt] = hv;
                }
            }
#pragma unroll
            for (int kk = 0; kk < 4; ++kk) {
                const int s = 8 + pass * 4 + kk;
                PIPE_SYNC();
                STAGE(CHB((s + 3) & 15), ((s + 3) & 3) * 1024);
                const int cb = (s & 3) * 1024;
#pragma unroll
                for (int ks2 = 0; ks2 < 2; ++ks2) {
                    const int ks = kk * 2 + ks2;
                    short8 Bh[2];
#pragma unroll
                    for (int bt = 0; bt < 2; ++bt) {
                        u32x4 tb_ = {tph[bt][4*ks+0], tph[bt][4*ks+1],
                                     tph[bt][4*ks+2], tph[bt][4*ks+3]};
                        Bh[bt] = __builtin_bit_cast(short8, tb_);
                    }
#pragma unroll
                    for (int j = 0; j < 8; ++j) {
                        const short8 Ah = __builtin_bit_cast(short8,
                            wf[cb + ks2*512 + j*64 + lane]);
                        h4[0*16+pass*8+j] = __builtin_amdgcn_mfma_f32_16x16x32_bf16(Ah, Bh[0], h4[0*16+pass*8+j], 0, 0, 0);
                        h4[1*16+pass*8+j] = __builtin_amdgcn_mfma_f32_16x16x32_bf16(Ah, Bh[1], h4[1*16+pass*8+j], 0, 0, 0);
                    }
                }
            }
        }

        // ---------- norm clip (in regs, per tile) ----------
#pragma unroll
        for (int bt = 0; bt < 2; ++bt) {
            float ss = 0.0f;
#pragma unroll
            for (int mt = 0; mt < 16; ++mt)
#pragma unroll
                for (int r = 0; r < 4; ++r) ss += h4[bt*16+mt][r] * h4[bt*16+mt][r];
            ss += __shfl_xor(ss, 16);
            ss += __shfl_xor(ss, 32);
            const float n = sqrtf(ss);
            const float sc = (n > 10.0f) ? (10.0f / (n + 1e-8f)) : 1.0f;
#pragma unroll
            for (int mt = 0; mt < 16; ++mt) {
                h4[bt*16+mt][0] *= sc; h4[bt*16+mt][1] *= sc;
                h4[bt*16+mt][2] *= sc; h4[bt*16+mt][3] *= sc;
            }
        }
    }

    // ---------- store h_final ----------
#pragma unroll
    for (int bt = 0; bt < 2; ++bt) {
#pragma unroll
        for (int mt = 0; mt < 16; ++mt) {
            float4 v;
            v.x = h4[bt*16+mt][0]; v.y = h4[bt*16+mt][1];
            v.z = h4[bt*16+mt][2]; v.w = h4[bt*16+mt][3];
            *(float4*)&out_h[(size_t)(bglob + bt*16) * DIMX + 16 * mt + 4 * G] = v;
        }
    }
}

extern "C" void kernel_launch(void* const* d_in, const int* in_sizes, int n_in,
                              void* d_out, int out_size, void* d_ws, size_t ws_size,
                              hipStream_t stream) {
    const float* h0      = (const float*)d_in[0];
    const float* W1      = (const float*)d_in[1];
    const float* b1      = (const float*)d_in[2];
    const float* W2      = (const float*)d_in[3];
    const float* b2      = (const float*)d_in[4];
    const float* anchors = (const float*)d_in[5];
    const int B = in_sizes[0] / DIMX;

    float* out_h     = (float*)d_out;
    float* out_align = out_h + (long long)B * DIMX;
    float* out_div   = out_align + (long long)NL * B * 3;
    float* out_tens  = out_div   + (long long)NL * B * 3;

    u32x4* ws = (u32x4*)d_ws;   // 256 KiB

    hipLaunchKernelGGL(wsplit, dim3(64), dim3(256), 0, stream, W1, W2, ws);
    hipLaunchKernelGGL(collapse_mfma16, dim3(B / 256), dim3(512), 0, stream,
                       h0, b1, b2, anchors, ws,
                       out_h, out_align, out_div, out_tens, B);
}